// Round 9
// baseline (27.550 us; speedup 1.0000x reference)
//
#include <hip/hip_runtime.h>
#include <math.h>

// Problem constants: B=256, N=64, M=64, d=32, TOPK=10
constexpr int Bn = 256;
constexpr int Nn = 64;
constexpr int Mn = 64;
constexpr int Dn = 32;
constexpr int TK = 10;
constexpr int NT = 1024;   // 16 waves

// Correctly-rounded fp32 exp via fp64 (matches np within <=0.5 ulp)
__device__ __forceinline__ float exp_np(float x) {
    return (float)exp((double)x);
}
// Monotone fp32 -> uint32 order map (weights finite; no NaNs)
__device__ __forceinline__ unsigned int f2u(float f) {
    unsigned int b = __float_as_uint(f);
    return (b & 0x80000000u) ? ~b : (b | 0x80000000u);
}
__device__ __forceinline__ float u2f(unsigned int u) {
    return __uint_as_float((u & 0x80000000u) ? (u ^ 0x80000000u) : ~u);
}

__global__ __launch_bounds__(NT) void sparse_lambda_attn_kernel(
    const float* __restrict__ fv,   // [B,N,D]
    const float* __restrict__ cv,   // [B,M,D]
    const float* __restrict__ Wq,   // [D,D]
    const float* __restrict__ Wk,   // [D,D]
    const float* __restrict__ Wv,   // [D,M]
    float* __restrict__ out)        // [B, N*TK, D]
{
    // Replicate numpy fp32 semantics: NO fma contraction anywhere in this kernel.
    #pragma clang fp contract(off)

    __shared__ float fT[Dn][65];       // 8.1 KB  [d][n]  (bank = (d+n)%32: conflict-free both ways)
    __shared__ float cT[Dn][65];       // 8.1 KB  [d][m]
    __shared__ float c_lds[Mn][36];    // 9 KB    [m][d] row-major padded (for output-phase f4 reads)
    __shared__ float KpT[Dn][68];      // 8.5 KB  [k][m]  K probabilities (written once, post-softmax)
    __shared__ float QmT[Dn][68];      // 8.5 KB  [k][n]
    __shared__ float VwS[Mn][68];      // 17 KB   [m][v] V  -> (aliased) weight [n][v]
    __shared__ float lamS[Dn][68];     // 8.5 KB  [k][v]
    __shared__ float topw[Nn][TK];     // 2.5 KB
    __shared__ int   topi[Nn][TK];     // 2.5 KB
    // total ~72.9 KB -> 2 blocks/CU

    const int b    = blockIdx.x;
    const int tid  = threadIdx.x;
    const int lane = tid & 63;
    const int wid  = tid >> 6;

    // ---- stage: f -> fT ; c -> c_lds + cT (coalesced f4 global reads) ----
    if (tid < 512) {
        const float4 v = reinterpret_cast<const float4*>(fv + (size_t)b * Nn * Dn)[tid];
        const int n = tid >> 3, d4 = (tid & 7) << 2;
        fT[d4 + 0][n] = v.x; fT[d4 + 1][n] = v.y; fT[d4 + 2][n] = v.z; fT[d4 + 3][n] = v.w;
    } else {
        const int t = tid - 512;
        const float4 v = reinterpret_cast<const float4*>(cv + (size_t)b * Mn * Dn)[t];
        const int m = t >> 3, d4 = (t & 7) << 2;
        *reinterpret_cast<float4*>(&c_lds[m][d4]) = v;
        cT[d4 + 0][m] = v.x; cT[d4 + 1][m] = v.y; cT[d4 + 2][m] = v.z; cT[d4 + 3][m] = v.w;
    }
    __syncthreads();

    // ---- Phase A (single barrier): K+softmax on waves 0-7; Q and V on waves 8-15.
    // W matrices read via wave-uniform pointers -> scalar cache (s_load), off the LDS pipe.
    if (wid < 8) {
        // K columns 4w..4w+3; lane = m. Sequential ascending-d mul-then-add (np-exact).
        const int kq = __builtin_amdgcn_readfirstlane(wid);
        const int m = lane;
        const float* wkq = Wk + (kq << 2);
        float a0 = 0.f, a1 = 0.f, a2 = 0.f, a3 = 0.f;
        #pragma unroll 4
        for (int d = 0; d < Dn; ++d) {
            const float cc = cT[d][m];
            const float* wr = wkq + d * Dn;
            const float w0 = wr[0], w1 = wr[1], w2 = wr[2], w3 = wr[3];
            a0 = a0 + cc * w0;  a1 = a1 + cc * w1;  a2 = a2 + cc * w2;  a3 = a3 + cc * w3;
        }
        // column max: xor shuffle tree (fmax is exactly order-independent); all lanes get it
        float m0 = a0, m1 = a1, m2 = a2, m3 = a3;
        #pragma unroll
        for (int off = 1; off < 64; off <<= 1) {
            m0 = fmaxf(m0, __shfl_xor(m0, off));
            m1 = fmaxf(m1, __shfl_xor(m1, off));
            m2 = fmaxf(m2, __shfl_xor(m2, off));
            m3 = fmaxf(m3, __shfl_xor(m3, off));
        }
        // exp (np: whole array first), then ascending-m ordered sum via readlane chain
        const float e0 = exp_np(a0 - m0);
        const float e1 = exp_np(a1 - m1);
        const float e2 = exp_np(a2 - m2);
        const float e3 = exp_np(a3 - m3);
        float s0 = 0.f, s1 = 0.f, s2 = 0.f, s3 = 0.f;
        #pragma unroll
        for (int t = 0; t < 64; ++t) {   // s = (((e(0)+e(1))+e(2))+...) — np.sum order
            s0 = s0 + __shfl(e0, t);
            s1 = s1 + __shfl(e1, t);
            s2 = s2 + __shfl(e2, t);
            s3 = s3 + __shfl(e3, t);
        }
        // true division, store final probabilities (stride-1 across lanes: conflict-free)
        KpT[(kq << 2) + 0][m] = e0 / s0;
        KpT[(kq << 2) + 1][m] = e1 / s1;
        KpT[(kq << 2) + 2][m] = e2 / s2;
        KpT[(kq << 2) + 3][m] = e3 / s3;
    } else {
        // Q columns 4q..4q+3 AND V columns 8q..8q+7; lane = n (= m)
        const int q = __builtin_amdgcn_readfirstlane(wid - 8);
        const int nm = lane;
        const float* wqq = Wq + (q << 2);
        const float* wvq = Wv + (q << 3);
        float a0 = 0.f, a1 = 0.f, a2 = 0.f, a3 = 0.f;
        float b0 = 0.f, b1 = 0.f, b2 = 0.f, b3 = 0.f, b4 = 0.f, b5 = 0.f, b6 = 0.f, b7 = 0.f;
        #pragma unroll 4
        for (int d = 0; d < Dn; ++d) {
            const float ff = fT[d][nm];
            const float cc = cT[d][nm];
            const float* wr = wqq + d * Dn;
            const float* ur = wvq + d * Mn;
            const float w0 = wr[0], w1 = wr[1], w2 = wr[2], w3 = wr[3];
            const float u0 = ur[0], u1 = ur[1], u2 = ur[2], u3 = ur[3];
            const float u4 = ur[4], u5 = ur[5], u6 = ur[6], u7 = ur[7];
            a0 = a0 + ff * w0;  a1 = a1 + ff * w1;  a2 = a2 + ff * w2;  a3 = a3 + ff * w3;
            b0 = b0 + cc * u0;  b1 = b1 + cc * u1;  b2 = b2 + cc * u2;  b3 = b3 + cc * u3;
            b4 = b4 + cc * u4;  b5 = b5 + cc * u5;  b6 = b6 + cc * u6;  b7 = b7 + cc * u7;
        }
        QmT[(q << 2) + 0][nm] = a0;
        QmT[(q << 2) + 1][nm] = a1;
        QmT[(q << 2) + 2][nm] = a2;
        QmT[(q << 2) + 3][nm] = a3;
        float4 r0; r0.x = b0; r0.y = b1; r0.z = b2; r0.w = b3;
        float4 r1; r1.x = b4; r1.y = b5; r1.z = b6; r1.w = b7;
        *reinterpret_cast<float4*>(&VwS[nm][(q << 3) + 0]) = r0;
        *reinterpret_cast<float4*>(&VwS[nm][(q << 3) + 4]) = r1;
    }
    __syncthreads();

    // ---- lam[k][v] = sum_m K[m][k]*V[m][v]: 512 threads, (k, v4), ascending m ----
    if (tid < 512) {
        const int k = tid >> 4, v4 = (tid & 15) << 2;
        float a0 = 0.f, a1 = 0.f, a2 = 0.f, a3 = 0.f;
        for (int m = 0; m < Mn; ++m) {
            const float kk = KpT[k][m];
            const float4 vv = *reinterpret_cast<const float4*>(&VwS[m][v4]);
            a0 = a0 + kk * vv.x;  a1 = a1 + kk * vv.y;  a2 = a2 + kk * vv.z;  a3 = a3 + kk * vv.w;
        }
        float4 r; r.x = a0; r.y = a1; r.z = a2; r.w = a3;
        *reinterpret_cast<float4*>(&lamS[k][v4]) = r;
    }
    __syncthreads();

    // ---- weight[n][v] = sum_k Q[n][k]*lam[k][v]: 1024 threads, (n, v4); write over VwS ----
    {
        const int n = tid >> 4, v4 = (tid & 15) << 2;
        float a0 = 0.f, a1 = 0.f, a2 = 0.f, a3 = 0.f;
        for (int k = 0; k < Dn; ++k) {
            const float qq = QmT[k][n];
            const float4 lv = *reinterpret_cast<const float4*>(&lamS[k][v4]);
            a0 = a0 + qq * lv.x;  a1 = a1 + qq * lv.y;  a2 = a2 + qq * lv.z;  a3 = a3 + qq * lv.w;
        }
        float4 r; r.x = a0; r.y = a1; r.z = a2; r.w = a3;
        *reinterpret_cast<float4*>(&VwS[n][v4]) = r;   // VwS now holds weight[n][v]
    }
    __syncthreads();

    // ---- top-10 per row: 16-lane group per row; comparison-only (bit-exact ranking) ----
    {
        const int g = tid & 15;
        const int n = tid >> 4;

        const float4 s4 = *reinterpret_cast<const float4*>(&VwS[n][g << 2]);
        unsigned su0 = f2u(s4.x), su1 = f2u(s4.y), su2 = f2u(s4.z), su3 = f2u(s4.w);
        unsigned avail = 0xFu;

        float val0 = 0.f, myval = 0.f;
        int   myidx = 0;

        #pragma unroll
        for (int t = 0; t < TK; ++t) {
            unsigned bu = 0u; int bm = 64;
            if ((avail & 1u) && su0 > bu) { bu = su0; bm = (g << 2) + 0; }
            if ((avail & 2u) && su1 > bu) { bu = su1; bm = (g << 2) + 1; }
            if ((avail & 4u) && su2 > bu) { bu = su2; bm = (g << 2) + 2; }
            if ((avail & 8u) && su3 > bu) { bu = su3; bm = (g << 2) + 3; }
            #pragma unroll
            for (int off = 1; off <= 8; off <<= 1) {
                const unsigned ou = __shfl_xor(bu, off);
                const int      om = __shfl_xor(bm, off);
                if (ou > bu || (ou == bu && om < bm)) { bu = ou; bm = om; }
            }
            const float bv = u2f(bu);
            if (t == 0) val0 = bv;
            if (g == t) { myval = bv; myidx = bm; }
            if ((bm >> 2) == g) avail &= ~(1u << (bm & 3));
        }

        const float ev_own = (g < TK) ? exp_np(myval - val0) : 0.f;
        float s = 0.f;
        #pragma unroll
        for (int t = 0; t < TK; ++t) {
            const float e = __shfl(ev_own, (lane & 48) + t);
            s = s + e;
        }
        if (g < TK) {
            topw[n][g] = ev_own / s;
            topi[n][g] = myidx;
        }
    }
    __syncthreads();

    // ---- output: out[b][n*TK+t][d] = w * (f[n][d]*c[idx][d]), f4-coalesced stores ----
    float* ob = out + (size_t)b * (Nn * TK * Dn);
    constexpr int TOT4 = Nn * TK * Dn / 4;   // 5120 float4 per batch
    for (int i = tid; i < TOT4; i += NT) {
        const int n = i / (TK * Dn / 4);            // / 80
        const int r = i - n * (TK * Dn / 4);
        const int t = r >> 3;
        const int d4 = (r & 7) << 2;
        const float w = topw[n][t];
        const int m = topi[n][t];
        const float f0 = fT[d4 + 0][n];
        const float f1 = fT[d4 + 1][n];
        const float f2 = fT[d4 + 2][n];
        const float f3 = fT[d4 + 3][n];
        const float4 c4 = *reinterpret_cast<const float4*>(&c_lds[m][d4]);
        float4 o;
        { const float vx = f0 * c4.x; o.x = w * vx; }
        { const float vy = f1 * c4.y; o.y = w * vy; }
        { const float vz = f2 * c4.z; o.z = w * vz; }
        { const float vw = f3 * c4.w; o.w = w * vw; }
        reinterpret_cast<float4*>(ob)[i] = o;
    }
}

extern "C" void kernel_launch(void* const* d_in, const int* in_sizes, int n_in,
                              void* d_out, int out_size, void* d_ws, size_t ws_size,
                              hipStream_t stream) {
    const float* fv = (const float*)d_in[0];   // featureVec [256,64,32]
    const float* cv = (const float*)d_in[1];   // contextVec [256,64,32]
    const float* Wq = (const float*)d_in[2];   // [32,32]
    const float* Wk = (const float*)d_in[3];   // [32,32]
    const float* Wv = (const float*)d_in[4];   // [32,64]
    float* out = (float*)d_out;                // [256, 640, 32]

    sparse_lambda_attn_kernel<<<Bn, NT, 0, stream>>>(fv, cv, Wq, Wk, Wv, out);
}